// Round 3
// baseline (135.328 us; speedup 1.0000x reference)
//
#include <hip/hip_runtime.h>
#include <stdint.h>
#include <stddef.h>

typedef int v4i __attribute__((ext_vector_type(4)));

#define GLOAD_LDS16(g, l) __builtin_amdgcn_global_load_lds( \
    (const __attribute__((address_space(1))) void*)(g),     \
    (__attribute__((address_space(3))) void*)(l), 16, 0, 0)

// ---------------------------------------------------------------------------
// Quantize rows of length 2048: one wave per row, 4 rows per 256-thread block.
// scale = max(amax/127, floorv); q = clip(rint(v/scale), -128, 127)
// ---------------------------------------------------------------------------
__device__ __forceinline__ int pack4(float4 f, float s) {
    int a = (int)rintf(f.x / s); a = a < -128 ? -128 : (a > 127 ? 127 : a);
    int b = (int)rintf(f.y / s); b = b < -128 ? -128 : (b > 127 ? 127 : b);
    int c = (int)rintf(f.z / s); c = c < -128 ? -128 : (c > 127 ? 127 : c);
    int d = (int)rintf(f.w / s); d = d < -128 ? -128 : (d > 127 ? 127 : d);
    return (a & 255) | ((b & 255) << 8) | ((c & 255) << 16) | ((d & 255) << 24);
}

__global__ __launch_bounds__(256) void quant_rows_2048(
    const float* __restrict__ in, signed char* __restrict__ q,
    float* __restrict__ scales, float floorv)
{
    const int lane = threadIdx.x & 63;
    const int row  = blockIdx.x * 4 + (threadIdx.x >> 6);
    const float* rp = in + (size_t)row * 2048;

    float4 v[8];
#pragma unroll
    for (int j = 0; j < 2; ++j) {
        const float4* p = (const float4*)(rp + j * 1024 + lane * 16);
#pragma unroll
        for (int i = 0; i < 4; ++i) v[j * 4 + i] = p[i];
    }
    float am = 0.0f;
#pragma unroll
    for (int i = 0; i < 8; ++i) {
        am = fmaxf(am, fabsf(v[i].x));
        am = fmaxf(am, fabsf(v[i].y));
        am = fmaxf(am, fabsf(v[i].z));
        am = fmaxf(am, fabsf(v[i].w));
    }
#pragma unroll
    for (int off = 32; off; off >>= 1) am = fmaxf(am, __shfl_xor(am, off));
    const float s = fmaxf(am / 127.0f, floorv);

#pragma unroll
    for (int j = 0; j < 2; ++j) {
        int4 pk;
        pk.x = pack4(v[j * 4 + 0], s);
        pk.y = pack4(v[j * 4 + 1], s);
        pk.z = pack4(v[j * 4 + 2], s);
        pk.w = pack4(v[j * 4 + 3], s);
        *(int4*)(q + (size_t)row * 2048 + j * 1024 + lane * 16) = pk;
    }
    if (lane == 0) scales[row] = s;
}

// ---------------------------------------------------------------------------
// Pipelined int8 GEMM, register-double-buffered phases.
// 256x256 tile, BK=64, 512 thr = 8 waves (2M x 4N), per-wave 128x64 via
// 8x4 frags of mfma_i32_16x16x64_i8. 4-deep LDS ring (128 KB), 3 tiles ahead.
// Each phase: issue 3 ds_reads for NEXT phase (2 A + 1 next-tile B),
// 1 global_load_lds for tile t+3, BAR, lgkmcnt(3)+sched_barrier(0),
// 8 MFMA on regs loaded LAST phase, BAR. Tile-end vmcnt(4) (never 0 mid-loop)
// keeps t+1,t+2 resident so next-tile B prefetch is legal.
// Swizzle: lds slot s of row r holds global chunk s ^ ((r>>1)&3), both sides.
// ---------------------------------------------------------------------------
__global__ __launch_bounds__(512, 2) void gemm_i8_pipe(
    const signed char* __restrict__ xq, const signed char* __restrict__ wq,
    const float* __restrict__ xs, const float* __restrict__ ws,
    const float* __restrict__ bias, float* __restrict__ out, int K)
{
    __shared__ __align__(16) signed char lds[131072]; // [A:4x16KB][B:4x16KB]

    const int tid  = threadIdx.x;
    const int lane = tid & 63;
    const int wid  = tid >> 6;
    const int wm   = wid >> 2;        // 0..1
    const int wn   = wid & 3;         // 0..3

    const int nwg  = gridDim.x * gridDim.y;
    int orig = blockIdx.y * gridDim.x + blockIdx.x;
    int swz  = ((nwg & 7) == 0) ? ((orig & 7) * (nwg >> 3) + (orig >> 3)) : orig;
    const int brow = (swz / gridDim.x) * 256;
    const int bcol = (swz % gridDim.x) * 256;

    const int srow = tid >> 2;                                   // 0..127
    const int gch  = (((tid & 3) ^ ((tid >> 3) & 3)) << 4);      // swizzled src byte
    const int lofs = tid << 4;                                   // linear LDS dest
    const signed char* gA = xq + (size_t)(brow + srow) * K;
    const signed char* gB = wq + (size_t)(bcol + srow) * K;

#define ST_A(tt, half) GLOAD_LDS16(gA + (size_t)(half) * 128 * K + (size_t)(tt) * 64 + gch, \
                                   lds + ((((tt) & 3) << 14) + ((half) << 13) + lofs))
#define ST_B(tt, half) GLOAD_LDS16(gB + (size_t)(half) * 128 * K + (size_t)(tt) * 64 + gch, \
                                   lds + (65536 + (((tt) & 3) << 14) + ((half) << 13) + lofs))

    const int rl   = lane & 15;
    const int ko   = lane >> 4;
    const int slot = ((ko ^ ((rl >> 1) & 3)) << 4);

#define FRAG_A(buf, r) (*(const v4i*)(lds + (((buf) << 14) + (r) * 64 + slot)))
#define FRAG_B(buf, r) (*(const v4i*)(lds + (65536 + ((buf) << 14) + (r) * 64 + slot)))

    v4i acc[8][4] = {};
    const int ar = wm * 128 + rl;
    const int br = wn * 64 + rl;

#define MFMA8(M0, M1)                                                              \
    do {                                                                           \
        __builtin_amdgcn_s_setprio(1);                                             \
        acc[M0][0] = __builtin_amdgcn_mfma_i32_16x16x64_i8(a0, bc0, acc[M0][0], 0, 0, 0); \
        acc[M0][1] = __builtin_amdgcn_mfma_i32_16x16x64_i8(a0, bc1, acc[M0][1], 0, 0, 0); \
        acc[M0][2] = __builtin_amdgcn_mfma_i32_16x16x64_i8(a0, bc2, acc[M0][2], 0, 0, 0); \
        acc[M0][3] = __builtin_amdgcn_mfma_i32_16x16x64_i8(a0, bc3, acc[M0][3], 0, 0, 0); \
        acc[M1][0] = __builtin_amdgcn_mfma_i32_16x16x64_i8(a1, bc0, acc[M1][0], 0, 0, 0); \
        acc[M1][1] = __builtin_amdgcn_mfma_i32_16x16x64_i8(a1, bc1, acc[M1][1], 0, 0, 0); \
        acc[M1][2] = __builtin_amdgcn_mfma_i32_16x16x64_i8(a1, bc2, acc[M1][2], 0, 0, 0); \
        acc[M1][3] = __builtin_amdgcn_mfma_i32_16x16x64_i8(a1, bc3, acc[M1][3], 0, 0, 0); \
        __builtin_amdgcn_s_setprio(0);                                             \
    } while (0)

#define BAR()   __builtin_amdgcn_s_barrier()
#define LGKM3() do { asm volatile("s_waitcnt lgkmcnt(3)" ::: "memory"); \
                     __builtin_amdgcn_sched_barrier(0); } while (0)

    // ---- prologue: stage tiles 0,1,2; vmcnt(4) => tiles 0,1 resident
    ST_A(0, 0); ST_A(0, 1); ST_B(0, 0); ST_B(0, 1);
    ST_A(1, 0); ST_A(1, 1); ST_B(1, 0); ST_B(1, 1);
    ST_A(2, 0); ST_A(2, 1); ST_B(2, 0); ST_B(2, 1);
    asm volatile("s_waitcnt vmcnt(4)" ::: "memory");
    BAR();

    // preload tile-0 registers (6 reads)
    v4i bc0 = FRAG_B(0, br);
    v4i bc1 = FRAG_B(0, br + 16);
    v4i bc2 = FRAG_B(0, br + 32);
    v4i bc3 = FRAG_B(0, br + 48);
    v4i a0  = FRAG_A(0, ar);
    v4i a1  = FRAG_A(0, ar + 16);
    v4i bn0, bn1, bn2, bn3, na0, na1;

    const int NT = K >> 6;   // 32
    for (int t = 0; t < NT; ++t) {
        const int buf  = t & 3;
        const int nbuf = (t + 1) & 3;
        const bool st  = (t + 3 < NT);
        // ---- phase 0
        na0 = FRAG_A(buf, ar + 32); na1 = FRAG_A(buf, ar + 48); bn0 = FRAG_B(nbuf, br);
        if (st) ST_A(t + 3, 0);
        BAR(); LGKM3();
        MFMA8(0, 1);
        BAR();
        a0 = na0; a1 = na1;
        // ---- phase 1
        na0 = FRAG_A(buf, ar + 64); na1 = FRAG_A(buf, ar + 80); bn1 = FRAG_B(nbuf, br + 16);
        if (st) ST_A(t + 3, 1);
        BAR(); LGKM3();
        MFMA8(2, 3);
        BAR();
        a0 = na0; a1 = na1;
        // ---- phase 2
        na0 = FRAG_A(buf, ar + 96); na1 = FRAG_A(buf, ar + 112); bn2 = FRAG_B(nbuf, br + 32);
        if (st) ST_B(t + 3, 0);
        BAR(); LGKM3();
        MFMA8(4, 5);
        BAR();
        a0 = na0; a1 = na1;
        // ---- phase 3: prefetch next tile's first A pair + last B frag
        na0 = FRAG_A(nbuf, ar); na1 = FRAG_A(nbuf, ar + 16); bn3 = FRAG_B(nbuf, br + 48);
        if (st) ST_B(t + 3, 1);
        BAR(); LGKM3();
        MFMA8(6, 7);
        if (t + 4 == NT)      asm volatile("s_waitcnt vmcnt(0)" ::: "memory");
        else if (t + 4 < NT)  asm volatile("s_waitcnt vmcnt(4)" ::: "memory");
        BAR();
        a0 = na0; a1 = na1;
        bc0 = bn0; bc1 = bn1; bc2 = bn2; bc3 = bn3;
    }

    // ---- epilogue: C/D layout col = lane&15, row = (lane>>4)*4 + j
    const int rg = lane >> 4;
#pragma unroll
    for (int n = 0; n < 4; ++n) {
        const int col = bcol + wn * 64 + n * 16 + rl;
        const float wsc = ws[col];
        const float bv  = bias[col];
#pragma unroll
        for (int m = 0; m < 8; ++m) {
#pragma unroll
            for (int j = 0; j < 4; ++j) {
                const int row = brow + wm * 128 + m * 16 + rg * 4 + j;
                out[(size_t)row * 2048 + col] =
                    (float)acc[m][n][j] * xs[row] * wsc + bv;
            }
        }
    }
#undef ST_A
#undef ST_B
#undef FRAG_A
#undef FRAG_B
#undef MFMA8
#undef BAR
#undef LGKM3
}

// ---------------------------------------------------------------------------
extern "C" void kernel_launch(void* const* d_in, const int* in_sizes, int n_in,
                              void* d_out, int out_size, void* d_ws, size_t ws_size,
                              hipStream_t stream) {
    const float* x    = (const float*)d_in[0];   // [B,N,D] = [4,4096,2048]
    const float* w    = (const float*)d_in[1];   // [O,D]   = [2048,2048]
    const float* bias = (const float*)d_in[2];   // [O]
    float* out = (float*)d_out;

    const int D = 2048;
    const int O = in_sizes[2];                   // 2048
    const int M = in_sizes[0] / D;               // 16384

    char* wsb = (char*)d_ws;
    signed char* xq  = (signed char*)wsb;
    signed char* wqp = (signed char*)(wsb + (size_t)M * D);
    float* xs  = (float*)(wsb + (size_t)M * D + (size_t)O * D);
    float* wsc = (float*)(wsb + (size_t)M * D + (size_t)O * D + (size_t)M * 4);

    quant_rows_2048<<<M / 4, 256, 0, stream>>>(x, xq, xs, 1e-12f);
    quant_rows_2048<<<O / 4, 256, 0, stream>>>(w, wqp, wsc, 1e-8f / 127.0f);

    dim3 grid(O / 256, M / 256);   // (8, 64) = 512 blocks
    gemm_i8_pipe<<<grid, 512, 0, stream>>>(xq, wqp, xs, wsc, bias, out, D);
}

// Round 4
// 125.346 us; speedup vs baseline: 1.0796x; 1.0796x over previous
//
#include <hip/hip_runtime.h>
#include <stdint.h>
#include <stddef.h>

typedef int v4i __attribute__((ext_vector_type(4)));

#define GLOAD_LDS16(g, l) __builtin_amdgcn_global_load_lds( \
    (const __attribute__((address_space(1))) void*)(g),     \
    (__attribute__((address_space(3))) void*)(l), 16, 0, 0)

// ---------------------------------------------------------------------------
// Quantize rows of length 2048: one wave per row, 4 rows per 256-thread block.
// scale = max(amax/127, floorv); q = clip(rint(v/scale), -128, 127)
// ---------------------------------------------------------------------------
__device__ __forceinline__ int pack4(float4 f, float s) {
    int a = (int)rintf(f.x / s); a = a < -128 ? -128 : (a > 127 ? 127 : a);
    int b = (int)rintf(f.y / s); b = b < -128 ? -128 : (b > 127 ? 127 : b);
    int c = (int)rintf(f.z / s); c = c < -128 ? -128 : (c > 127 ? 127 : c);
    int d = (int)rintf(f.w / s); d = d < -128 ? -128 : (d > 127 ? 127 : d);
    return (a & 255) | ((b & 255) << 8) | ((c & 255) << 16) | ((d & 255) << 24);
}

__global__ __launch_bounds__(256) void quant_rows_2048(
    const float* __restrict__ in, signed char* __restrict__ q,
    float* __restrict__ scales, float floorv)
{
    const int lane = threadIdx.x & 63;
    const int row  = blockIdx.x * 4 + (threadIdx.x >> 6);
    const float* rp = in + (size_t)row * 2048;

    float4 v[8];
#pragma unroll
    for (int j = 0; j < 2; ++j) {
        const float4* p = (const float4*)(rp + j * 1024 + lane * 16);
#pragma unroll
        for (int i = 0; i < 4; ++i) v[j * 4 + i] = p[i];
    }
    float am = 0.0f;
#pragma unroll
    for (int i = 0; i < 8; ++i) {
        am = fmaxf(am, fabsf(v[i].x));
        am = fmaxf(am, fabsf(v[i].y));
        am = fmaxf(am, fabsf(v[i].z));
        am = fmaxf(am, fabsf(v[i].w));
    }
#pragma unroll
    for (int off = 32; off; off >>= 1) am = fmaxf(am, __shfl_xor(am, off));
    const float s = fmaxf(am / 127.0f, floorv);

#pragma unroll
    for (int j = 0; j < 2; ++j) {
        int4 pk;
        pk.x = pack4(v[j * 4 + 0], s);
        pk.y = pack4(v[j * 4 + 1], s);
        pk.z = pack4(v[j * 4 + 2], s);
        pk.w = pack4(v[j * 4 + 3], s);
        *(int4*)(q + (size_t)row * 2048 + j * 1024 + lane * 16) = pk;
    }
    if (lane == 0) scales[row] = s;
}

// ---------------------------------------------------------------------------
// Pipelined int8 GEMM — ONE barrier per K-tile (ring-4 makes phase barriers
// unnecessary: stages of tile t write buf (t+3)&3; reads in tile t touch
// (t)&3,(t+1)&3; max drift = 1 tile => writer (t+4)&3 vs reader (t+1..t+2)&3
// disjoint). Waves drift within a tile so the per-CU LDS pipe overlaps the
// per-SIMD MFMA pipes across waves.
// 256x256 tile, BK=64, 8 waves (2Mx4N), per-wave 128x64, mfma_i32_16x16x64_i8.
// Phase: {3 ds_reads for next phase; 1 gload t+3; lgkmcnt(3)+sched_barrier;
// setprio(1) 8xMFMA setprio(0)}. Tile end: vmcnt(4)+barrier (never 0 until
// the pipeline drains at t==NT-3).
// ---------------------------------------------------------------------------
__global__ __launch_bounds__(512, 2) void gemm_i8_pipe(
    const signed char* __restrict__ xq, const signed char* __restrict__ wq,
    const float* __restrict__ xs, const float* __restrict__ ws,
    const float* __restrict__ bias, float* __restrict__ out, int K)
{
    __shared__ __align__(16) signed char lds[131072]; // [A:4x16KB][B:4x16KB]

    const int tid  = threadIdx.x;
    const int lane = tid & 63;
    const int wid  = tid >> 6;
    const int wm   = wid >> 2;        // 0..1
    const int wn   = wid & 3;         // 0..3

    const int nwg  = gridDim.x * gridDim.y;
    int orig = blockIdx.y * gridDim.x + blockIdx.x;
    int swz  = ((nwg & 7) == 0) ? ((orig & 7) * (nwg >> 3) + (orig >> 3)) : orig;
    const int brow = (swz / gridDim.x) * 256;
    const int bcol = (swz % gridDim.x) * 256;

    const int srow = tid >> 2;                                   // 0..127
    const int gch  = (((tid & 3) ^ ((tid >> 3) & 3)) << 4);      // swizzled src byte
    const int lofs = tid << 4;                                   // linear LDS dest
    const signed char* gA = xq + (size_t)(brow + srow) * K;
    const signed char* gB = wq + (size_t)(bcol + srow) * K;

#define ST_A(tt, half) GLOAD_LDS16(gA + (size_t)(half) * 128 * K + (size_t)(tt) * 64 + gch, \
                                   lds + ((((tt) & 3) << 14) + ((half) << 13) + lofs))
#define ST_B(tt, half) GLOAD_LDS16(gB + (size_t)(half) * 128 * K + (size_t)(tt) * 64 + gch, \
                                   lds + (65536 + (((tt) & 3) << 14) + ((half) << 13) + lofs))

    const int rl   = lane & 15;
    const int ko   = lane >> 4;
    const int slot = ((ko ^ ((rl >> 1) & 3)) << 4);

#define FRAG_A(buf, r) (*(const v4i*)(lds + (((buf) << 14) + (r) * 64 + slot)))
#define FRAG_B(buf, r) (*(const v4i*)(lds + (65536 + ((buf) << 14) + (r) * 64 + slot)))

    v4i acc[8][4] = {};
    const int ar = wm * 128 + rl;
    const int br = wn * 64 + rl;

#define MFMA8(M0, M1)                                                              \
    do {                                                                           \
        __builtin_amdgcn_s_setprio(1);                                             \
        acc[M0][0] = __builtin_amdgcn_mfma_i32_16x16x64_i8(a0, bc0, acc[M0][0], 0, 0, 0); \
        acc[M0][1] = __builtin_amdgcn_mfma_i32_16x16x64_i8(a0, bc1, acc[M0][1], 0, 0, 0); \
        acc[M0][2] = __builtin_amdgcn_mfma_i32_16x16x64_i8(a0, bc2, acc[M0][2], 0, 0, 0); \
        acc[M0][3] = __builtin_amdgcn_mfma_i32_16x16x64_i8(a0, bc3, acc[M0][3], 0, 0, 0); \
        acc[M1][0] = __builtin_amdgcn_mfma_i32_16x16x64_i8(a1, bc0, acc[M1][0], 0, 0, 0); \
        acc[M1][1] = __builtin_amdgcn_mfma_i32_16x16x64_i8(a1, bc1, acc[M1][1], 0, 0, 0); \
        acc[M1][2] = __builtin_amdgcn_mfma_i32_16x16x64_i8(a1, bc2, acc[M1][2], 0, 0, 0); \
        acc[M1][3] = __builtin_amdgcn_mfma_i32_16x16x64_i8(a1, bc3, acc[M1][3], 0, 0, 0); \
        __builtin_amdgcn_s_setprio(0);                                             \
    } while (0)

#define BAR()   __builtin_amdgcn_s_barrier()
#define LGKM3() do { asm volatile("s_waitcnt lgkmcnt(3)" ::: "memory"); \
                     __builtin_amdgcn_sched_barrier(0); } while (0)

    // ---- prologue: stage tiles 0,1,2; vmcnt(4) => tiles 0,1 resident
    ST_A(0, 0); ST_A(0, 1); ST_B(0, 0); ST_B(0, 1);
    ST_A(1, 0); ST_A(1, 1); ST_B(1, 0); ST_B(1, 1);
    ST_A(2, 0); ST_A(2, 1); ST_B(2, 0); ST_B(2, 1);
    asm volatile("s_waitcnt vmcnt(4)" ::: "memory");
    BAR();

    // preload tile-0 registers (6 reads; drained by first LGKM3)
    v4i bc0 = FRAG_B(0, br);
    v4i bc1 = FRAG_B(0, br + 16);
    v4i bc2 = FRAG_B(0, br + 32);
    v4i bc3 = FRAG_B(0, br + 48);
    v4i a0  = FRAG_A(0, ar);
    v4i a1  = FRAG_A(0, ar + 16);
    v4i bn0, bn1, bn2, bn3, na0, na1;

    const int NT = K >> 6;   // 32
    for (int t = 0; t < NT; ++t) {
        const int buf  = t & 3;
        const int nbuf = (t + 1) & 3;
        const bool st  = (t + 3 < NT);
        // ---- phase 0 (no barrier)
        na0 = FRAG_A(buf, ar + 32); na1 = FRAG_A(buf, ar + 48); bn0 = FRAG_B(nbuf, br);
        if (st) ST_A(t + 3, 0);
        LGKM3();
        MFMA8(0, 1);
        a0 = na0; a1 = na1;
        // ---- phase 1
        na0 = FRAG_A(buf, ar + 64); na1 = FRAG_A(buf, ar + 80); bn1 = FRAG_B(nbuf, br + 16);
        if (st) ST_A(t + 3, 1);
        LGKM3();
        MFMA8(2, 3);
        a0 = na0; a1 = na1;
        // ---- phase 2
        na0 = FRAG_A(buf, ar + 96); na1 = FRAG_A(buf, ar + 112); bn2 = FRAG_B(nbuf, br + 32);
        if (st) ST_B(t + 3, 0);
        LGKM3();
        MFMA8(4, 5);
        a0 = na0; a1 = na1;
        // ---- phase 3: next tile's first A pair + last B frag
        na0 = FRAG_A(nbuf, ar); na1 = FRAG_A(nbuf, ar + 16); bn3 = FRAG_B(nbuf, br + 48);
        if (st) ST_B(t + 3, 1);
        LGKM3();
        MFMA8(6, 7);
        // ---- tile boundary: single barrier while stages are in flight
        if (t < NT - 3) {
            asm volatile("s_waitcnt vmcnt(4)" ::: "memory");  // t+2 resident; only t+3 in flight
            BAR();
        } else if (t == NT - 3) {
            asm volatile("s_waitcnt vmcnt(0)" ::: "memory");  // drain NT-1 (issued 2 tiles ago)
        }                                                      // t > NT-3: read-only, no hazard
        a0 = na0; a1 = na1;
        bc0 = bn0; bc1 = bn1; bc2 = bn2; bc3 = bn3;
    }

    // ---- epilogue: C/D layout col = lane&15, row = (lane>>4)*4 + j
    const int rg = lane >> 4;
#pragma unroll
    for (int n = 0; n < 4; ++n) {
        const int col = bcol + wn * 64 + n * 16 + rl;
        const float wsc = ws[col];
        const float bv  = bias[col];
#pragma unroll
        for (int m = 0; m < 8; ++m) {
#pragma unroll
            for (int j = 0; j < 4; ++j) {
                const int row = brow + wm * 128 + m * 16 + rg * 4 + j;
                out[(size_t)row * 2048 + col] =
                    (float)acc[m][n][j] * xs[row] * wsc + bv;
            }
        }
    }
#undef ST_A
#undef ST_B
#undef FRAG_A
#undef FRAG_B
#undef MFMA8
#undef BAR
#undef LGKM3
}

// ---------------------------------------------------------------------------
extern "C" void kernel_launch(void* const* d_in, const int* in_sizes, int n_in,
                              void* d_out, int out_size, void* d_ws, size_t ws_size,
                              hipStream_t stream) {
    const float* x    = (const float*)d_in[0];   // [B,N,D] = [4,4096,2048]
    const float* w    = (const float*)d_in[1];   // [O,D]   = [2048,2048]
    const float* bias = (const float*)d_in[2];   // [O]
    float* out = (float*)d_out;

    const int D = 2048;
    const int O = in_sizes[2];                   // 2048
    const int M = in_sizes[0] / D;               // 16384

    char* wsb = (char*)d_ws;
    signed char* xq  = (signed char*)wsb;
    signed char* wqp = (signed char*)(wsb + (size_t)M * D);
    float* xs  = (float*)(wsb + (size_t)M * D + (size_t)O * D);
    float* wsc = (float*)(wsb + (size_t)M * D + (size_t)O * D + (size_t)M * 4);

    quant_rows_2048<<<M / 4, 256, 0, stream>>>(x, xq, xs, 1e-12f);
    quant_rows_2048<<<O / 4, 256, 0, stream>>>(w, wqp, wsc, 1e-8f / 127.0f);

    dim3 grid(O / 256, M / 256);   // (8, 64) = 512 blocks
    gemm_i8_pipe<<<grid, 512, 0, stream>>>(xq, wqp, xs, wsc, bias, out, D);
}